// Round 1
// baseline (13571.893 us; speedup 1.0000x reference)
//
#include <hip/hip_runtime.h>
#include <stdint.h>

typedef unsigned long long u64;
typedef unsigned short u16;

#define Bb   8
#define Tt   2048
#define Dd   1280
#define Ii   5120
#define BFn  4096
#define EPS  1e-5f
#define MARGIN 0.1f    // approx-gap threshold for exact fp32 rescore (err ~2e-5)

#define BK   16
#define LDT  132   // 128 + 4 pad (fp32 gemm)

typedef short bfx8 __attribute__((ext_vector_type(8)));  // 8 bf16 (4 VGPRs)
typedef float fx4  __attribute__((ext_vector_type(4)));  // MFMA C/D

// sortable key: min over key == min over float (handles negatives)
__device__ __forceinline__ unsigned fkey(float f) {
    unsigned u = __float_as_uint(f);
    return (u & 0x80000000u) ? ~u : (u | 0x80000000u);
}
__device__ __forceinline__ float unfkey(unsigned k) {
    unsigned u = (k & 0x80000000u) ? (k & 0x7FFFFFFFu) : ~k;
    return __uint_as_float(u);
}
__device__ __forceinline__ u64 shfl_xor_u64(u64 v, int mask) {
    unsigned lo = (unsigned)__shfl_xor((int)(unsigned)(v & 0xFFFFFFFFull), mask, 64);
    unsigned hi = (unsigned)__shfl_xor((int)(unsigned)(v >> 32), mask, 64);
    return ((u64)hi << 32) | (u64)lo;
}
__device__ __forceinline__ void top2_ins(u64& b1, u64& b2, u64 v) {
    if (v < b1) { b2 = b1; b1 = v; } else if (v < b2) b2 = v;
}
// LDS 16B-chunk swizzle: row stride = 64B(=16 banks); XOR spreads 16 rows
// over 8 chunk-slots twice -> 2-way (free) ds_read_b128.
__device__ __forceinline__ int swz(int r) { return (r & 3) ^ ((r >> 2) & 1); }

__device__ __forceinline__ void gload16(const u16* g, u16* l) {
    __builtin_amdgcn_global_load_lds(
        (const __attribute__((address_space(1))) void*)g,
        (__attribute__((address_space(3))) void*)l, 16, 0, 0);
}
// RNE bf16 split: x = hi + lo + O(2^-18 |x|)
__device__ __forceinline__ void bfsplit(float x, u16& h, u16& l) {
    unsigned u = __float_as_uint(x);
    unsigned hb = (u + 0x7FFFu + ((u >> 16) & 1u)) & 0xFFFF0000u;
    h = (u16)(hb >> 16);
    float rem = x - __uint_as_float(hb);
    unsigned u2 = __float_as_uint(rem);
    l = (u16)((u2 + 0x7FFFu + ((u2 >> 16) & 1u)) >> 16);
}

// ---------------- codebook row norms (exact fp32) ----------------
__global__ __launch_bounds__(256) void norms_kernel(
        const float* __restrict__ cb0, const float* __restrict__ cb1,
        const float* __restrict__ cb2, const float* __restrict__ cb3,
        float* __restrict__ norms) {
    int r = blockIdx.x;
    const float* row;
    if (r < 8192)       row = cb0 + (size_t)r * Ii;
    else if (r < 16384) row = cb1 + (size_t)(r - 8192) * Ii;
    else if (r < 20480) row = cb2 + (size_t)(r - 16384) * Ii;
    else                row = cb3 + (size_t)(r - 20480) * Ii;
    float s = 0.f;
    for (int i = threadIdx.x * 4; i < Ii; i += 1024) {
        float4 v = *(const float4*)(row + i);
        s += v.x * v.x + v.y * v.y + v.z * v.z + v.w * v.w;
    }
    __shared__ float red[4];
    for (int off = 32; off; off >>= 1) s += __shfl_down(s, off, 64);
    if ((threadIdx.x & 63) == 0) red[threadIdx.x >> 6] = s;
    __syncthreads();
    if (threadIdx.x == 0) norms[r] = red[0] + red[1] + red[2] + red[3];
}

// ---------------- Xp[bf][j] = x[b, 4f+(j&3), j>>2]  (j = d*4+k) ----------------
__global__ __launch_bounds__(256) void permute_kernel(
        const float* __restrict__ x, float* __restrict__ Xp) {
    int bf = blockIdx.x;
    int b = bf >> 9, f = bf & 511;
    const float* xrow = x + ((size_t)b * Tt + 4 * f) * Dd;
    float* outp = Xp + (size_t)bf * Ii;
    for (int j = threadIdx.x; j < Ii; j += 256) {
        outp[j] = xrow[(j & 3) * Dd + (j >> 2)];
    }
}

// ---------------- fp32 GEMM: C[m][n] = sum_k A[m][k] * B[n][k] ----------------
__global__ __launch_bounds__(256, 3) void gemm_nt(
        const float* __restrict__ A, const float* __restrict__ Bm,
        float* __restrict__ C, int N, int K) {
    __shared__ float As[BK][LDT];
    __shared__ float Bs[BK][LDT];
    const int m0 = blockIdx.x * 128;
    const int n0 = blockIdx.y * 128;
    const int t  = threadIdx.x;
    const int tx = t & 15, ty = t >> 4;
    const int lrow = t >> 2;
    const int lkc  = (t & 3) << 2;

    const float* Ap0 = A  + (size_t)(m0 + lrow) * K + lkc;
    const float* Ap1 = Ap0 + (size_t)64 * K;
    const float* Bp0 = Bm + (size_t)(n0 + lrow) * K + lkc;
    const float* Bp1 = Bp0 + (size_t)64 * K;

    float acc[8][8];
#pragma unroll
    for (int i = 0; i < 8; ++i)
#pragma unroll
        for (int j = 0; j < 8; ++j) acc[i][j] = 0.f;

    for (int k0 = 0; k0 < K; k0 += BK) {
        float4 a0 = *(const float4*)(Ap0 + k0);
        float4 a1 = *(const float4*)(Ap1 + k0);
        float4 b0 = *(const float4*)(Bp0 + k0);
        float4 b1 = *(const float4*)(Bp1 + k0);
        __syncthreads();
        As[lkc + 0][lrow] = a0.x; As[lkc + 1][lrow] = a0.y;
        As[lkc + 2][lrow] = a0.z; As[lkc + 3][lrow] = a0.w;
        As[lkc + 0][lrow + 64] = a1.x; As[lkc + 1][lrow + 64] = a1.y;
        As[lkc + 2][lrow + 64] = a1.z; As[lkc + 3][lrow + 64] = a1.w;
        Bs[lkc + 0][lrow] = b0.x; Bs[lkc + 1][lrow] = b0.y;
        Bs[lkc + 2][lrow] = b0.z; Bs[lkc + 3][lrow] = b0.w;
        Bs[lkc + 0][lrow + 64] = b1.x; Bs[lkc + 1][lrow + 64] = b1.y;
        Bs[lkc + 2][lrow + 64] = b1.z; Bs[lkc + 3][lrow + 64] = b1.w;
        __syncthreads();
#pragma unroll
        for (int kk = 0; kk < BK; ++kk) {
            float a[8], b[8];
            *(float4*)(a)     = *(const float4*)(&As[kk][ty * 4]);
            *(float4*)(a + 4) = *(const float4*)(&As[kk][ty * 4 + 64]);
            *(float4*)(b)     = *(const float4*)(&Bs[kk][tx * 4]);
            *(float4*)(b + 4) = *(const float4*)(&Bs[kk][tx * 4 + 64]);
#pragma unroll
            for (int i = 0; i < 8; ++i)
#pragma unroll
                for (int j = 0; j < 8; ++j)
                    acc[i][j] = fmaf(a[i], b[j], acc[i][j]);
        }
    }
#pragma unroll
    for (int ih = 0; ih < 2; ++ih)
#pragma unroll
        for (int r = 0; r < 4; ++r) {
            int row = m0 + ih * 64 + ty * 4 + r;
            float* cp = C + (size_t)row * N + n0;
            float4 v;
            v.x = acc[ih * 4 + r][0]; v.y = acc[ih * 4 + r][1];
            v.z = acc[ih * 4 + r][2]; v.w = acc[ih * 4 + r][3];
            *(float4*)(cp + tx * 4) = v;
            v.x = acc[ih * 4 + r][4]; v.y = acc[ih * 4 + r][5];
            v.z = acc[ih * 4 + r][6]; v.w = acc[ih * 4 + r][7];
            *(float4*)(cp + 64 + tx * 4) = v;
        }
}

// ---------------- split fp32 plane into bf16 hi/lo planes ----------------
__global__ __launch_bounds__(256) void split_kernel(
        const float* __restrict__ src, u16* __restrict__ hi,
        u16* __restrict__ lo) {
    const size_t idx = ((size_t)blockIdx.x * 256 + threadIdx.x) * 4;
    float4 v = *(const float4*)(src + idx);
    ushort4 h, l;
    bfsplit(v.x, h.x, l.x);
    bfsplit(v.y, h.y, l.y);
    bfsplit(v.z, h.z, l.z);
    bfsplit(v.w, h.w, l.w);
    *(ushort4*)(hi + idx) = h;
    *(ushort4*)(lo + idx) = l;
}

// ---------------- bf16x3 MFMA score GEMM + fused top-2 argmin ----------------
// score[m][c] = norms[c] - 2*(rHi.eHi + rLo.eHi + rHi.eLo)  (K' = 3*5120)
// m97 structure: 128x128 tile, BK=32, global_load_lds w16, 16x16x32 bf16 MFMA.
__global__ __launch_bounds__(256) void score_mfma(
        const u16* __restrict__ rHi, const u16* __restrict__ rLo,
        const u16* __restrict__ eHi, const u16* __restrict__ eLo,
        const float* __restrict__ normsCb, int colBase,
        u64* __restrict__ best, u64* __restrict__ second) {
    __shared__ __align__(16) u16 As[128 * 32];
    __shared__ __align__(16) u16 Bs[128 * 32];
    const int t    = threadIdx.x;
    const int lane = t & 63;
    const int wid  = t >> 6;
    const int wr   = wid >> 1, wc = wid & 1;       // 2x2 waves, 64x64 out each
    const int m0   = blockIdx.x * 128;
    const int n0   = blockIdx.y * 128;

    // staging: thread handles physical 16B-chunks t and t+256 of each tile.
    // physical chunk p holds logical (row=p>>2, cc=(p&3)^swz(row))  [rule 21:
    // linear LDS dest + inverse-swizzled global source + swizzled read]
    const int ar0 = t >> 2,        ac0 = (t & 3) ^ swz(ar0);
    const int ar1 = (t + 256) >> 2, ac1 = ((t + 256) & 3) ^ swz(ar1);
    const size_t gA0 = (size_t)(m0 + ar0) * Ii + ac0 * 8;
    const size_t gA1 = (size_t)(m0 + ar1) * Ii + ac1 * 8;
    const size_t gB0 = (size_t)(n0 + ar0) * Ii + ac0 * 8;
    const size_t gB1 = (size_t)(n0 + ar1) * Ii + ac1 * 8;
    u16* ldsA0 = &As[(wid * 64) * 8];        // wave-uniform bases (+lane*16 by HW)
    u16* ldsA1 = &As[(256 + wid * 64) * 8];
    u16* ldsB0 = &Bs[(wid * 64) * 8];
    u16* ldsB1 = &Bs[(256 + wid * 64) * 8];

    // fragment LDS offsets (A: row=l&15, k-chunk=l>>4; B symmetric for NT)
    const int r15 = lane & 15, j4 = lane >> 4;
    int aOff[4], bOff[4];
#pragma unroll
    for (int m = 0; m < 4; ++m) {
        int rowA = wr * 64 + m * 16 + r15;
        aOff[m] = (rowA * 4 + (j4 ^ swz(rowA))) * 8;
        int rowB = wc * 64 + m * 16 + r15;
        bOff[m] = (rowB * 4 + (j4 ^ swz(rowB))) * 8;
    }

    fx4 acc[4][4];
#pragma unroll
    for (int m = 0; m < 4; ++m)
#pragma unroll
        for (int n = 0; n < 4; ++n) acc[m][n] = (fx4){0.f, 0.f, 0.f, 0.f};

    // 3 error-compensation segments: (rHi,eHi), (rLo,eHi), (rHi,eLo)
#pragma unroll 1
    for (int seg = 0; seg < 3; ++seg) {
        const u16* Ap = (seg == 1) ? rLo : rHi;
        const u16* Bp = (seg == 2) ? eLo : eHi;
#pragma unroll 1
        for (int kk = 0; kk < Ii; kk += 32) {
            __syncthreads();                       // readers of prev tile done
            gload16(Ap + gA0 + kk, ldsA0);
            gload16(Ap + gA1 + kk, ldsA1);
            gload16(Bp + gB0 + kk, ldsB0);
            gload16(Bp + gB1 + kk, ldsB1);
            __syncthreads();                       // vmcnt(0) drained by compiler
            bfx8 a[4], b[4];
#pragma unroll
            for (int m = 0; m < 4; ++m) a[m] = *(const bfx8*)&As[aOff[m]];
#pragma unroll
            for (int n = 0; n < 4; ++n) b[n] = *(const bfx8*)&Bs[bOff[n]];
#pragma unroll
            for (int m = 0; m < 4; ++m)
#pragma unroll
                for (int n = 0; n < 4; ++n)
                    acc[m][n] = __builtin_amdgcn_mfma_f32_16x16x32_bf16(
                        a[m], b[n], acc[m][n], 0, 0, 0);
        }
    }

    // fused epilogue: per-row top-2 over this wave's 64 cols, then global
    // atomicMin displacement protocol (exact top-2 of all submissions).
    // C/D layout: col = lane&15, row = (lane>>4)*4 + reg  [m89-verified]
#pragma unroll
    for (int m = 0; m < 4; ++m) {
#pragma unroll
        for (int r = 0; r < 4; ++r) {
            const int row = m0 + wr * 64 + m * 16 + j4 * 4 + r;
            u64 b1 = ~0ull, b2 = ~0ull;
#pragma unroll
            for (int n = 0; n < 4; ++n) {
                const int cg = colBase + n0 + wc * 64 + n * 16 + r15;
                float s = normsCb[cg] - 2.f * acc[m][n][r];
                u64 pk = ((u64)fkey(s) << 32) | (u64)(unsigned)cg;
                top2_ins(b1, b2, pk);
            }
#pragma unroll
            for (int mask = 1; mask <= 8; mask <<= 1) {
                u64 o1 = shfl_xor_u64(b1, mask);
                u64 o2 = shfl_xor_u64(b2, mask);
                u64 m1 = b1 < o1 ? b1 : o1;
                u64 hi = b1 < o1 ? o1 : b1;
                u64 mn = b2 < o2 ? b2 : o2;
                b2 = hi < mn ? hi : mn;
                b1 = m1;
            }
            if (r15 == 0) {
                u64 old = atomicMin(&best[row], b1);
                u64 d = old > b1 ? old : b1;
                atomicMin(&second[row], d);    // displaced candidate
                atomicMin(&second[row], b2);   // this group's runner-up
            }
        }
    }
}

// ---------------- exact fp32 rescore when approx gap < MARGIN ----------------
__global__ __launch_bounds__(256) void fixup_kernel(
        const float* __restrict__ RES, const float* __restrict__ cb,
        const float* __restrict__ normsCb, u64* __restrict__ best,
        const u64* __restrict__ second) {
    const int bf = blockIdx.x;
    const u64 p1 = best[bf], p2 = second[bf];
    const float s1 = unfkey((unsigned)(p1 >> 32));
    const float s2 = unfkey((unsigned)(p2 >> 32));
    if (s2 - s1 > MARGIN) return;              // uniform branch
    const int id1 = (int)(unsigned)(p1 & 0xFFFFFFFFull);
    const int id2 = (int)(unsigned)(p2 & 0xFFFFFFFFull);
    const float* r  = RES + (size_t)bf * Ii;
    const float* c1 = cb + (size_t)id1 * Ii;
    const float* c2 = cb + (size_t)id2 * Ii;
    float d1 = 0.f, d2 = 0.f;
    for (int i = threadIdx.x * 4; i < Ii; i += 1024) {
        float4 rv = *(const float4*)(r + i);
        float4 a = *(const float4*)(c1 + i);
        float4 b = *(const float4*)(c2 + i);
        d1 += rv.x * a.x + rv.y * a.y + rv.z * a.z + rv.w * a.w;
        d2 += rv.x * b.x + rv.y * b.y + rv.z * b.z + rv.w * b.w;
    }
    __shared__ float red1[4], red2[4];
    for (int off = 32; off; off >>= 1) {
        d1 += __shfl_down(d1, off, 64);
        d2 += __shfl_down(d2, off, 64);
    }
    if ((threadIdx.x & 63) == 0) {
        red1[threadIdx.x >> 6] = d1;
        red2[threadIdx.x >> 6] = d2;
    }
    __syncthreads();
    if (threadIdx.x == 0) {
        float e1 = normsCb[id1] - 2.f * (red1[0] + red1[1] + red1[2] + red1[3]);
        float e2 = normsCb[id2] - 2.f * (red2[0] + red2[1] + red2[2] + red2[3]);
        u64 k1 = ((u64)fkey(e1) << 32) | (u64)(unsigned)id1;
        u64 k2 = ((u64)fkey(e2) << 32) | (u64)(unsigned)id2;
        best[bf] = k1 < k2 ? k1 : k2;          // exact winner, tie -> lower id
    }
}

// ---------------- h = silu(g) * u, in place over G ----------------
__global__ __launch_bounds__(256) void silu_mul_kernel(
        float* __restrict__ G, const float* __restrict__ U) {
    size_t idx = ((size_t)blockIdx.x * 256 + threadIdx.x) * 4;
    float4 g = *(float4*)(G + idx);
    float4 u = *(const float4*)(U + idx);
    g.x = g.x / (1.f + expf(-g.x)) * u.x;
    g.y = g.y / (1.f + expf(-g.y)) * u.y;
    g.z = g.z / (1.f + expf(-g.z)) * u.z;
    g.w = g.w / (1.f + expf(-g.w)) * u.w;
    *(float4*)(G + idx) = g;
}

// ---------------- layernorm(c + xi) in place; init best/second ----------------
__global__ __launch_bounds__(256) void ln_init_kernel(
        float* __restrict__ RES, const float* __restrict__ x,
        const float* __restrict__ scale, const float* __restrict__ bias,
        u64* __restrict__ best, u64* __restrict__ second) {
    __shared__ float row[Ii];
    __shared__ float red[8];
    const int bf = blockIdx.x;
    const int b = bf >> 9, f = bf & 511;
    const float* xrow = x + ((size_t)b * Tt + 4 * f) * Dd;
    float* r = RES + (size_t)bf * Ii;

    float s = 0.f;
    for (int i = threadIdx.x * 4; i < Ii; i += 1024) {
        float4 c = *(const float4*)(r + i);
        float4 xi = *(const float4*)(xrow + i);
        c.x += xi.x; c.y += xi.y; c.z += xi.z; c.w += xi.w;
        *(float4*)(row + i) = c;
        s += c.x + c.y + c.z + c.w;
    }
    for (int off = 32; off; off >>= 1) s += __shfl_down(s, off, 64);
    if ((threadIdx.x & 63) == 0) red[threadIdx.x >> 6] = s;
    __syncthreads();
    if (threadIdx.x == 0) red[4] = (red[0] + red[1] + red[2] + red[3]) / (float)Ii;
    __syncthreads();
    const float mu = red[4];

    float vs = 0.f;
    for (int i = threadIdx.x * 4; i < Ii; i += 1024) {
        float4 c = *(const float4*)(row + i);
        float dx = c.x - mu, dy = c.y - mu, dz = c.z - mu, dw = c.w - mu;
        vs += dx * dx + dy * dy + dz * dz + dw * dw;
    }
    for (int off = 32; off; off >>= 1) vs += __shfl_down(vs, off, 64);
    if ((threadIdx.x & 63) == 0) red[threadIdx.x >> 6] = vs;
    __syncthreads();
    if (threadIdx.x == 0) {
        float var = (red[0] + red[1] + red[2] + red[3]) / (float)Ii;
        red[5] = 1.0f / sqrtf(var + EPS);
    }
    __syncthreads();
    const float rs = red[5];

    for (int i = threadIdx.x * 4; i < Ii; i += 1024) {
        float4 c = *(const float4*)(row + i);
        float4 sc = *(const float4*)(scale + i);
        float4 bi = *(const float4*)(bias + i);
        c.x = (c.x - mu) * rs * sc.x + bi.x;
        c.y = (c.y - mu) * rs * sc.y + bi.y;
        c.z = (c.z - mu) * rs * sc.z + bi.z;
        c.w = (c.w - mu) * rs * sc.w + bi.w;
        *(float4*)(r + i) = c;
    }
    if (threadIdx.x == 0) { best[bf] = ~0ull; second[bf] = ~0ull; }
}

// ---------------- emit id, subtract chosen code, re-init best ----------------
__global__ __launch_bounds__(256) void update_kernel(
        float* __restrict__ RES, const float* __restrict__ cb,
        u64* __restrict__ best, u64* __restrict__ second,
        int* __restrict__ outp, const int* __restrict__ lens, int t, int do_sub) {
    const int bf = blockIdx.x;
    const u64 pk = best[bf];
    __syncthreads();
    const int id = (int)(unsigned)(pk & 0xFFFFFFFFull);
    if (threadIdx.x == 0) {
        int b = bf >> 9, f = bf & 511;
        outp[bf * 4 + t] = (f < lens[b]) ? id : 0;
        best[bf] = ~0ull;
        second[bf] = ~0ull;
    }
    if (do_sub) {
        const float* e = cb + (size_t)id * Ii;
        float* r = RES + (size_t)bf * Ii;
        for (int i = threadIdx.x * 4; i < Ii; i += 1024) {
            float4 rv = *(float4*)(r + i);
            float4 ev = *(const float4*)(e + i);
            rv.x -= ev.x; rv.y -= ev.y; rv.z -= ev.z; rv.w -= ev.w;
            *(float4*)(r + i) = rv;
        }
    }
}

extern "C" void kernel_launch(void* const* d_in, const int* in_sizes, int n_in,
                              void* d_out, int out_size, void* d_ws, size_t ws_size,
                              hipStream_t stream) {
    const float* x     = (const float*)d_in[0];
    const int*   lens  = (const int*)d_in[1];
    const float* wgate = (const float*)d_in[2];
    const float* wup   = (const float*)d_in[3];
    const float* wdown = (const float*)d_in[4];
    const float* lns   = (const float*)d_in[5];
    const float* lnb   = (const float*)d_in[6];
    const float* cb[4] = {(const float*)d_in[7], (const float*)d_in[8],
                          (const float*)d_in[9], (const float*)d_in[10]};
    int* outp = (int*)d_out;

    const size_t NBF = (size_t)BFn * Ii;     // 20,971,520 elements
    float* buf0  = (float*)d_ws;             // Xp, later RES/residual
    float* buf1  = buf0 + NBF;               // G/H, later rHi|rLo bf16 planes
    float* buf2  = buf1 + NBF;               // U,   later eHi|eLo bf16 planes
    float* norms = buf2 + NBF;               // 24576 floats
    u64*   best  = (u64*)(norms + 24576);    // 4096 u64
    u64*   second = best + BFn;              // 4096 u64
    u16* rHi = (u16*)buf1;                   // NBF bf16
    u16* rLo = rHi + NBF;
    u16* eHi = (u16*)buf2;                   // 4096*Ii bf16 (codebook chunk)
    u16* eLo = eHi + NBF;

    norms_kernel<<<dim3(24576), dim3(256), 0, stream>>>(cb[0], cb[1], cb[2], cb[3], norms);
    permute_kernel<<<dim3(BFn), dim3(256), 0, stream>>>(x, buf0);
    gemm_nt<<<dim3(32, 40), dim3(256), 0, stream>>>(buf0, wgate, buf1, Ii, Ii);
    gemm_nt<<<dim3(32, 40), dim3(256), 0, stream>>>(buf0, wup,   buf2, Ii, Ii);
    silu_mul_kernel<<<dim3((unsigned)(NBF / 1024)), dim3(256), 0, stream>>>(buf1, buf2);
    gemm_nt<<<dim3(32, 40), dim3(256), 0, stream>>>(buf1, wdown, buf0, Ii, Ii);
    ln_init_kernel<<<dim3(BFn), dim3(256), 0, stream>>>(buf0, x, lns, lnb, best, second);

    const int csz[4] = {8192, 8192, 4096, 4096};
    int noff = 0;
    for (int tcb = 0; tcb < 4; ++tcb) {
        split_kernel<<<dim3(20480), dim3(256), 0, stream>>>(buf0, rHi, rLo);
        for (int c0 = 0; c0 < csz[tcb]; c0 += 4096) {
            split_kernel<<<dim3(20480), dim3(256), 0, stream>>>(
                cb[tcb] + (size_t)c0 * Ii, eHi, eLo);
            score_mfma<<<dim3(32, 32), dim3(256), 0, stream>>>(
                rHi, rLo, eHi, eLo, norms + noff, c0, best, second);
        }
        fixup_kernel<<<dim3(BFn), dim3(256), 0, stream>>>(
            buf0, cb[tcb], norms + noff, best, second);
        update_kernel<<<dim3(BFn), dim3(256), 0, stream>>>(
            buf0, cb[tcb], best, second, outp, lens, tcb, tcb < 3 ? 1 : 0);
        noff += csz[tcb];
    }
    (void)in_sizes; (void)n_in; (void)out_size; (void)ws_size;
}

// Round 3
// 9557.175 us; speedup vs baseline: 1.4201x; 1.4201x over previous
//
#include <hip/hip_runtime.h>
#include <stdint.h>

typedef unsigned long long u64;
typedef unsigned short u16;

#define Bb   8
#define Tt   2048
#define Dd   1280
#define Ii   5120
#define BFn  4096
#define EPS  1e-5f
#define MARGIN 0.1f    // approx-gap threshold for exact fp32 rescore (err ~2e-5)

typedef short bfx8 __attribute__((ext_vector_type(8)));  // 8 bf16 (4 VGPRs)
typedef float fx4  __attribute__((ext_vector_type(4)));  // MFMA C/D

// sortable key: min over key == min over float (handles negatives)
__device__ __forceinline__ unsigned fkey(float f) {
    unsigned u = __float_as_uint(f);
    return (u & 0x80000000u) ? ~u : (u | 0x80000000u);
}
__device__ __forceinline__ float unfkey(unsigned k) {
    unsigned u = (k & 0x80000000u) ? (k & 0x7FFFFFFFu) : ~k;
    return __uint_as_float(u);
}
__device__ __forceinline__ u64 shfl_xor_u64(u64 v, int mask) {
    unsigned lo = (unsigned)__shfl_xor((int)(unsigned)(v & 0xFFFFFFFFull), mask, 64);
    unsigned hi = (unsigned)__shfl_xor((int)(unsigned)(v >> 32), mask, 64);
    return ((u64)hi << 32) | (u64)lo;
}
__device__ __forceinline__ void top2_ins(u64& b1, u64& b2, u64 v) {
    if (v < b1) { b2 = b1; b1 = v; } else if (v < b2) b2 = v;
}
// LDS 16B-chunk swizzle (BK=32 bf16 rows = 4 chunks): rows 0..7 permute the
// 4 chunk slots -> 16 lanes at fixed logical chunk hit 8 (parity,chunk) bank
// groups twice = 2-way = free (m136).
__device__ __forceinline__ int swz(int r) { return (r & 3) ^ ((r >> 2) & 1); }

__device__ __forceinline__ void gload16(const u16* g, u16* l) {
    __builtin_amdgcn_global_load_lds(
        (const __attribute__((address_space(1))) void*)g,
        (__attribute__((address_space(3))) void*)l, 16, 0, 0);
}
// RNE bf16 split: x = hi + lo + O(2^-18 |x|)   (score path)
__device__ __forceinline__ void bfsplit(float x, u16& h, u16& l) {
    unsigned u = __float_as_uint(x);
    unsigned hb = (u + 0x7FFFu + ((u >> 16) & 1u)) & 0xFFFF0000u;
    h = (u16)(hb >> 16);
    float rem = x - __uint_as_float(hb);
    unsigned u2 = __float_as_uint(rem);
    l = (u16)((u2 + 0x7FFFu + ((u2 >> 16) & 1u)) >> 16);
}
// EXACT 3-way truncation split: x == hi + mid + lo (fp32 mantissa 24 = 3x8).
// All subtractions Sterbenz-exact; lo holds the final 8 bits exactly.
__device__ __forceinline__ void tsplit3(float x, u16& h, u16& m, u16& l) {
    unsigned u = __float_as_uint(x);
    unsigned hb = u & 0xFFFF0000u;
    h = (u16)(hb >> 16);
    float r1 = x - __uint_as_float(hb);
    unsigned u1 = __float_as_uint(r1);
    unsigned mb = u1 & 0xFFFF0000u;
    m = (u16)(mb >> 16);
    float r2 = r1 - __uint_as_float(mb);
    l = (u16)(__float_as_uint(r2) >> 16);
}
__device__ __forceinline__ void split_store(float4 v, u16* p0, u16* p1, u16* p2) {
    ushort4 h, m, l;
    tsplit3(v.x, h.x, m.x, l.x);
    tsplit3(v.y, h.y, m.y, l.y);
    tsplit3(v.z, h.z, m.z, l.z);
    tsplit3(v.w, h.w, m.w, l.w);
    *(ushort4*)p0 = h; *(ushort4*)p1 = m; *(ushort4*)p2 = l;
}

// ---------------- codebook row norms (exact fp32) ----------------
__global__ __launch_bounds__(256) void norms_kernel(
        const float* __restrict__ cb0, const float* __restrict__ cb1,
        const float* __restrict__ cb2, const float* __restrict__ cb3,
        float* __restrict__ norms) {
    int r = blockIdx.x;
    const float* row;
    if (r < 8192)       row = cb0 + (size_t)r * Ii;
    else if (r < 16384) row = cb1 + (size_t)(r - 8192) * Ii;
    else if (r < 20480) row = cb2 + (size_t)(r - 16384) * Ii;
    else                row = cb3 + (size_t)(r - 20480) * Ii;
    float s = 0.f;
    for (int i = threadIdx.x * 4; i < Ii; i += 1024) {
        float4 v = *(const float4*)(row + i);
        s += v.x * v.x + v.y * v.y + v.z * v.z + v.w * v.w;
    }
    __shared__ float red[4];
    for (int off = 32; off; off >>= 1) s += __shfl_down(s, off, 64);
    if ((threadIdx.x & 63) == 0) red[threadIdx.x >> 6] = s;
    __syncthreads();
    if (threadIdx.x == 0) norms[r] = red[0] + red[1] + red[2] + red[3];
}

// ---------------- Xp[bf][j] = x[b, 4f+(j&3), j>>2]  (j = d*4+k) ----------------
__global__ __launch_bounds__(256) void permute_kernel(
        const float* __restrict__ x, float* __restrict__ Xp) {
    int bf = blockIdx.x;
    int b = bf >> 9, f = bf & 511;
    const float* xrow = x + ((size_t)b * Tt + 4 * f) * Dd;
    float* outp = Xp + (size_t)bf * Ii;
    for (int j = threadIdx.x; j < Ii; j += 256) {
        outp[j] = xrow[(j & 3) * Dd + (j >> 2)];
    }
}

// ---------------- exact-fp32-accuracy MFMA GEMM via 3-way bf16 split ----------
// C[m][n] = sum_k A[m][k]*B[n][k]; per 32-K tile: in-register truncation split
// of fp32 operands into 3 bf16 LDS planes, then 6 cross-products
// {hh,hm,hl,mh,mm,lh} (dropped terms <= 2^-24 |ab| -- below fp32 noise).
#define MFMA16(AF, BF)                                                        \
    do {                                                                      \
        _Pragma("unroll")                                                     \
        for (int m_ = 0; m_ < 4; ++m_)                                        \
            _Pragma("unroll")                                                 \
            for (int n_ = 0; n_ < 4; ++n_)                                    \
                acc[m_][n_] = __builtin_amdgcn_mfma_f32_16x16x32_bf16(        \
                    (AF)[m_], (BF)[n_], acc[m_][n_], 0, 0, 0);                \
    } while (0)

__global__ __launch_bounds__(256, 2) void gemm6_nt(
        const float* __restrict__ A, const float* __restrict__ Bm,
        float* __restrict__ C, int N, int K) {
    __shared__ __align__(16) u16 As[3 * 4096];   // 3 planes [128][32] bf16
    __shared__ __align__(16) u16 Bs[3 * 4096];   // 48 KB total
    const int t    = threadIdx.x;
    const int lane = t & 63;
    const int wid  = t >> 6;
    const int wr   = wid >> 1, wc = wid & 1;     // 2x2 waves, 64x64 out each
    const int m0   = blockIdx.x * 128;
    const int n0   = blockIdx.y * 128;

    // fragment LDS offsets (u16 units): row*32 + physchunk*8
    const int r15 = lane & 15, j4 = lane >> 4;
    int aOff[4], bOff[4];
#pragma unroll
    for (int m = 0; m < 4; ++m) {
        int rowA = wr * 64 + m * 16 + r15;
        aOff[m] = rowA * 32 + ((j4 ^ swz(rowA)) << 3);
        int rowB = wc * 64 + m * 16 + r15;
        bOff[m] = rowB * 32 + ((j4 ^ swz(rowB)) << 3);
    }

    fx4 acc[4][4];
#pragma unroll
    for (int m = 0; m < 4; ++m)
#pragma unroll
        for (int n = 0; n < 4; ++n) acc[m][n] = (fx4){0.f, 0.f, 0.f, 0.f};

    // staging map: idx = s*256+t in [0,1024): row = idx>>3, kq = idx&7 (float4)
    float4 av[4], bv[4];
#pragma unroll
    for (int s = 0; s < 4; ++s) {
        const int idx = s * 256 + t, row = idx >> 3, kq = idx & 7;
        av[s] = *(const float4*)(A  + (size_t)(m0 + row) * K + kq * 4);
        bv[s] = *(const float4*)(Bm + (size_t)(n0 + row) * K + kq * 4);
    }

    for (int k0 = 0; k0 < K; k0 += 32) {
        __syncthreads();                          // prev-tile readers done
#pragma unroll
        for (int s = 0; s < 4; ++s) {
            const int idx = s * 256 + t, row = idx >> 3, kq = idx & 7;
            const int base = row * 32 + (((kq >> 1) ^ swz(row)) << 3)
                           + ((kq & 1) << 2);
            split_store(av[s], &As[base], &As[4096 + base], &As[8192 + base]);
            split_store(bv[s], &Bs[base], &Bs[4096 + base], &Bs[8192 + base]);
        }
        __syncthreads();
        // prefetch next tile AFTER barrier: loads fly during the MFMA phase
        if (k0 + 32 < K) {
#pragma unroll
            for (int s = 0; s < 4; ++s) {
                const int idx = s * 256 + t, row = idx >> 3, kq = idx & 7;
                av[s] = *(const float4*)(A  + (size_t)(m0 + row) * K + (k0 + 32) + kq * 4);
                bv[s] = *(const float4*)(Bm + (size_t)(n0 + row) * K + (k0 + 32) + kq * 4);
            }
        }
        // 6 products, grouped by A plane; B-hi kept resident
        bfx8 aF[4], bF[4], b0F[4];
#pragma unroll
        for (int i = 0; i < 4; ++i) b0F[i] = *(const bfx8*)&Bs[bOff[i]];
#pragma unroll
        for (int i = 0; i < 4; ++i) aF[i] = *(const bfx8*)&As[aOff[i]];
        MFMA16(aF, b0F);                                        // hh
#pragma unroll
        for (int i = 0; i < 4; ++i) bF[i] = *(const bfx8*)&Bs[4096 + bOff[i]];
        MFMA16(aF, bF);                                         // hm
#pragma unroll
        for (int i = 0; i < 4; ++i) bF[i] = *(const bfx8*)&Bs[8192 + bOff[i]];
        MFMA16(aF, bF);                                         // hl
#pragma unroll
        for (int i = 0; i < 4; ++i) aF[i] = *(const bfx8*)&As[4096 + aOff[i]];
        MFMA16(aF, b0F);                                        // mh
#pragma unroll
        for (int i = 0; i < 4; ++i) bF[i] = *(const bfx8*)&Bs[4096 + bOff[i]];
        MFMA16(aF, bF);                                         // mm
#pragma unroll
        for (int i = 0; i < 4; ++i) aF[i] = *(const bfx8*)&As[8192 + aOff[i]];
        MFMA16(aF, b0F);                                        // lh
    }

    // epilogue: C/D layout col = lane&15, row = (lane>>4)*4 + reg
#pragma unroll
    for (int m = 0; m < 4; ++m)
#pragma unroll
        for (int r = 0; r < 4; ++r) {
            const int row = m0 + wr * 64 + m * 16 + j4 * 4 + r;
            float* cp = C + (size_t)row * N + n0 + wc * 64 + r15;
#pragma unroll
            for (int n = 0; n < 4; ++n) cp[n * 16] = acc[m][n][r];
        }
}

// ---------------- split fp32 plane into bf16 hi/lo planes (score path) --------
__global__ __launch_bounds__(256) void split_kernel(
        const float* __restrict__ src, u16* __restrict__ hi,
        u16* __restrict__ lo) {
    const size_t idx = ((size_t)blockIdx.x * 256 + threadIdx.x) * 4;
    float4 v = *(const float4*)(src + idx);
    ushort4 h, l;
    bfsplit(v.x, h.x, l.x);
    bfsplit(v.y, h.y, l.y);
    bfsplit(v.z, h.z, l.z);
    bfsplit(v.w, h.w, l.w);
    *(ushort4*)(hi + idx) = h;
    *(ushort4*)(lo + idx) = l;
}

// ---------------- bf16x3 MFMA score GEMM + fused top-2 argmin ----------------
// score[m][c] = norms[c] - 2*(rHi.eHi + rLo.eHi + rHi.eLo)  (K' = 3*5120)
__global__ __launch_bounds__(256) void score_mfma(
        const u16* __restrict__ rHi, const u16* __restrict__ rLo,
        const u16* __restrict__ eHi, const u16* __restrict__ eLo,
        const float* __restrict__ normsCb, int colBase,
        u64* __restrict__ best, u64* __restrict__ second) {
    __shared__ __align__(16) u16 As[128 * 32];
    __shared__ __align__(16) u16 Bs[128 * 32];
    const int t    = threadIdx.x;
    const int lane = t & 63;
    const int wid  = t >> 6;
    const int wr   = wid >> 1, wc = wid & 1;       // 2x2 waves, 64x64 out each
    const int m0   = blockIdx.x * 128;
    const int n0   = blockIdx.y * 128;

    // staging: thread handles physical 16B-chunks t and t+256 of each tile.
    // physical chunk p holds logical (row=p>>2, cc=(p&3)^swz(row))  [rule 21]
    const int ar0 = t >> 2,        ac0 = (t & 3) ^ swz(ar0);
    const int ar1 = (t + 256) >> 2, ac1 = ((t + 256) & 3) ^ swz(ar1);
    const size_t gA0 = (size_t)(m0 + ar0) * Ii + ac0 * 8;
    const size_t gA1 = (size_t)(m0 + ar1) * Ii + ac1 * 8;
    const size_t gB0 = (size_t)(n0 + ar0) * Ii + ac0 * 8;
    const size_t gB1 = (size_t)(n0 + ar1) * Ii + ac1 * 8;
    u16* ldsA0 = &As[(wid * 64) * 8];        // wave-uniform bases (+lane*16 by HW)
    u16* ldsA1 = &As[(256 + wid * 64) * 8];
    u16* ldsB0 = &Bs[(wid * 64) * 8];
    u16* ldsB1 = &Bs[(256 + wid * 64) * 8];

    const int r15 = lane & 15, j4 = lane >> 4;
    int aOff[4], bOff[4];
#pragma unroll
    for (int m = 0; m < 4; ++m) {
        int rowA = wr * 64 + m * 16 + r15;
        aOff[m] = (rowA * 4 + (j4 ^ swz(rowA))) * 8;
        int rowB = wc * 64 + m * 16 + r15;
        bOff[m] = (rowB * 4 + (j4 ^ swz(rowB))) * 8;
    }

    fx4 acc[4][4];
#pragma unroll
    for (int m = 0; m < 4; ++m)
#pragma unroll
        for (int n = 0; n < 4; ++n) acc[m][n] = (fx4){0.f, 0.f, 0.f, 0.f};

    // 3 error-compensation segments: (rHi,eHi), (rLo,eHi), (rHi,eLo)
#pragma unroll 1
    for (int seg = 0; seg < 3; ++seg) {
        const u16* Ap = (seg == 1) ? rLo : rHi;
        const u16* Bp = (seg == 2) ? eLo : eHi;
#pragma unroll 1
        for (int kk = 0; kk < Ii; kk += 32) {
            __syncthreads();
            gload16(Ap + gA0 + kk, ldsA0);
            gload16(Ap + gA1 + kk, ldsA1);
            gload16(Bp + gB0 + kk, ldsB0);
            gload16(Bp + gB1 + kk, ldsB1);
            __syncthreads();
            bfx8 a[4], b[4];
#pragma unroll
            for (int m = 0; m < 4; ++m) a[m] = *(const bfx8*)&As[aOff[m]];
#pragma unroll
            for (int n = 0; n < 4; ++n) b[n] = *(const bfx8*)&Bs[bOff[n]];
#pragma unroll
            for (int m = 0; m < 4; ++m)
#pragma unroll
                for (int n = 0; n < 4; ++n)
                    acc[m][n] = __builtin_amdgcn_mfma_f32_16x16x32_bf16(
                        a[m], b[n], acc[m][n], 0, 0, 0);
        }
    }

    // fused epilogue: per-row top-2, then global atomicMin displacement protocol
#pragma unroll
    for (int m = 0; m < 4; ++m) {
#pragma unroll
        for (int r = 0; r < 4; ++r) {
            const int row = m0 + wr * 64 + m * 16 + j4 * 4 + r;
            u64 b1 = ~0ull, b2 = ~0ull;
#pragma unroll
            for (int n = 0; n < 4; ++n) {
                const int cg = colBase + n0 + wc * 64 + n * 16 + r15;
                float s = normsCb[cg] - 2.f * acc[m][n][r];
                u64 pk = ((u64)fkey(s) << 32) | (u64)(unsigned)cg;
                top2_ins(b1, b2, pk);
            }
#pragma unroll
            for (int mask = 1; mask <= 8; mask <<= 1) {
                u64 o1 = shfl_xor_u64(b1, mask);
                u64 o2 = shfl_xor_u64(b2, mask);
                u64 m1 = b1 < o1 ? b1 : o1;
                u64 hi = b1 < o1 ? o1 : b1;
                u64 mn = b2 < o2 ? b2 : o2;
                b2 = hi < mn ? hi : mn;
                b1 = m1;
            }
            if (r15 == 0) {
                u64 old = atomicMin(&best[row], b1);
                u64 d = old > b1 ? old : b1;
                atomicMin(&second[row], d);    // displaced candidate
                atomicMin(&second[row], b2);   // this group's runner-up
            }
        }
    }
}

// ---------------- exact fp32 rescore when approx gap < MARGIN ----------------
__global__ __launch_bounds__(256) void fixup_kernel(
        const float* __restrict__ RES, const float* __restrict__ cb,
        const float* __restrict__ normsCb, u64* __restrict__ best,
        const u64* __restrict__ second) {
    const int bf = blockIdx.x;
    const u64 p1 = best[bf], p2 = second[bf];
    const float s1 = unfkey((unsigned)(p1 >> 32));
    const float s2 = unfkey((unsigned)(p2 >> 32));
    if (s2 - s1 > MARGIN) return;              // uniform branch
    const int id1 = (int)(unsigned)(p1 & 0xFFFFFFFFull);
    const int id2 = (int)(unsigned)(p2 & 0xFFFFFFFFull);
    const float* r  = RES + (size_t)bf * Ii;
    const float* c1 = cb + (size_t)id1 * Ii;
    const float* c2 = cb + (size_t)id2 * Ii;
    float d1 = 0.f, d2 = 0.f;
    for (int i = threadIdx.x * 4; i < Ii; i += 1024) {
        float4 rv = *(const float4*)(r + i);
        float4 a = *(const float4*)(c1 + i);
        float4 b = *(const float4*)(c2 + i);
        d1 += rv.x * a.x + rv.y * a.y + rv.z * a.z + rv.w * a.w;
        d2 += rv.x * b.x + rv.y * b.y + rv.z * b.z + rv.w * b.w;
    }
    __shared__ float red1[4], red2[4];
    for (int off = 32; off; off >>= 1) {
        d1 += __shfl_down(d1, off, 64);
        d2 += __shfl_down(d2, off, 64);
    }
    if ((threadIdx.x & 63) == 0) {
        red1[threadIdx.x >> 6] = d1;
        red2[threadIdx.x >> 6] = d2;
    }
    __syncthreads();
    if (threadIdx.x == 0) {
        float e1 = normsCb[id1] - 2.f * (red1[0] + red1[1] + red1[2] + red1[3]);
        float e2 = normsCb[id2] - 2.f * (red2[0] + red2[1] + red2[2] + red2[3]);
        u64 k1 = ((u64)fkey(e1) << 32) | (u64)(unsigned)id1;
        u64 k2 = ((u64)fkey(e2) << 32) | (u64)(unsigned)id2;
        best[bf] = k1 < k2 ? k1 : k2;          // exact winner, tie -> lower id
    }
}

// ---------------- h = silu(g) * u, in place over G ----------------
__global__ __launch_bounds__(256) void silu_mul_kernel(
        float* __restrict__ G, const float* __restrict__ U) {
    size_t idx = ((size_t)blockIdx.x * 256 + threadIdx.x) * 4;
    float4 g = *(float4*)(G + idx);
    float4 u = *(const float4*)(U + idx);
    g.x = g.x / (1.f + expf(-g.x)) * u.x;
    g.y = g.y / (1.f + expf(-g.y)) * u.y;
    g.z = g.z / (1.f + expf(-g.z)) * u.z;
    g.w = g.w / (1.f + expf(-g.w)) * u.w;
    *(float4*)(G + idx) = g;
}

// ---------------- layernorm(c + xi) in place; init best/second ----------------
__global__ __launch_bounds__(256) void ln_init_kernel(
        float* __restrict__ RES, const float* __restrict__ x,
        const float* __restrict__ scale, const float* __restrict__ bias,
        u64* __restrict__ best, u64* __restrict__ second) {
    __shared__ float row[Ii];
    __shared__ float red[8];
    const int bf = blockIdx.x;
    const int b = bf >> 9, f = bf & 511;
    const float* xrow = x + ((size_t)b * Tt + 4 * f) * Dd;
    float* r = RES + (size_t)bf * Ii;

    float s = 0.f;
    for (int i = threadIdx.x * 4; i < Ii; i += 1024) {
        float4 c = *(const float4*)(r + i);
        float4 xi = *(const float4*)(xrow + i);
        c.x += xi.x; c.y += xi.y; c.z += xi.z; c.w += xi.w;
        *(float4*)(row + i) = c;
        s += c.x + c.y + c.z + c.w;
    }
    for (int off = 32; off; off >>= 1) s += __shfl_down(s, off, 64);
    if ((threadIdx.x & 63) == 0) red[threadIdx.x >> 6] = s;
    __syncthreads();
    if (threadIdx.x == 0) red[4] = (red[0] + red[1] + red[2] + red[3]) / (float)Ii;
    __syncthreads();
    const float mu = red[4];

    float vs = 0.f;
    for (int i = threadIdx.x * 4; i < Ii; i += 1024) {
        float4 c = *(const float4*)(row + i);
        float dx = c.x - mu, dy = c.y - mu, dz = c.z - mu, dw = c.w - mu;
        vs += dx * dx + dy * dy + dz * dz + dw * dw;
    }
    for (int off = 32; off; off >>= 1) vs += __shfl_down(vs, off, 64);
    if ((threadIdx.x & 63) == 0) red[threadIdx.x >> 6] = vs;
    __syncthreads();
    if (threadIdx.x == 0) {
        float var = (red[0] + red[1] + red[2] + red[3]) / (float)Ii;
        red[5] = 1.0f / sqrtf(var + EPS);
    }
    __syncthreads();
    const float rs = red[5];

    for (int i = threadIdx.x * 4; i < Ii; i += 1024) {
        float4 c = *(const float4*)(row + i);
        float4 sc = *(const float4*)(scale + i);
        float4 bi = *(const float4*)(bias + i);
        c.x = (c.x - mu) * rs * sc.x + bi.x;
        c.y = (c.y - mu) * rs * sc.y + bi.y;
        c.z = (c.z - mu) * rs * sc.z + bi.z;
        c.w = (c.w - mu) * rs * sc.w + bi.w;
        *(float4*)(r + i) = c;
    }
    if (threadIdx.x == 0) { best[bf] = ~0ull; second[bf] = ~0ull; }
}

// ---------------- emit id, subtract chosen code, re-init best ----------------
__global__ __launch_bounds__(256) void update_kernel(
        float* __restrict__ RES, const float* __restrict__ cb,
        u64* __restrict__ best, u64* __restrict__ second,
        int* __restrict__ outp, const int* __restrict__ lens, int t, int do_sub) {
    const int bf = blockIdx.x;
    const u64 pk = best[bf];
    __syncthreads();
    const int id = (int)(unsigned)(pk & 0xFFFFFFFFull);
    if (threadIdx.x == 0) {
        int b = bf >> 9, f = bf & 511;
        outp[bf * 4 + t] = (f < lens[b]) ? id : 0;
        best[bf] = ~0ull;
        second[bf] = ~0ull;
    }
    if (do_sub) {
        const float* e = cb + (size_t)id * Ii;
        float* r = RES + (size_t)bf * Ii;
        for (int i = threadIdx.x * 4; i < Ii; i += 1024) {
            float4 rv = *(float4*)(r + i);
            float4 ev = *(const float4*)(e + i);
            rv.x -= ev.x; rv.y -= ev.y; rv.z -= ev.z; rv.w -= ev.w;
            *(float4*)(r + i) = rv;
        }
    }
}

extern "C" void kernel_launch(void* const* d_in, const int* in_sizes, int n_in,
                              void* d_out, int out_size, void* d_ws, size_t ws_size,
                              hipStream_t stream) {
    const float* x     = (const float*)d_in[0];
    const int*   lens  = (const int*)d_in[1];
    const float* wgate = (const float*)d_in[2];
    const float* wup   = (const float*)d_in[3];
    const float* wdown = (const float*)d_in[4];
    const float* lns   = (const float*)d_in[5];
    const float* lnb   = (const float*)d_in[6];
    const float* cb[4] = {(const float*)d_in[7], (const float*)d_in[8],
                          (const float*)d_in[9], (const float*)d_in[10]};
    int* outp = (int*)d_out;

    const size_t NBF = (size_t)BFn * Ii;     // 20,971,520 elements
    float* buf0  = (float*)d_ws;             // Xp, later RES/residual
    float* buf1  = buf0 + NBF;               // G/H, later rHi|rLo bf16 planes
    float* buf2  = buf1 + NBF;               // U,   later eHi|eLo bf16 planes
    float* norms = buf2 + NBF;               // 24576 floats
    u64*   best  = (u64*)(norms + 24576);    // 4096 u64
    u64*   second = best + BFn;              // 4096 u64
    u16* rHi = (u16*)buf1;                   // NBF bf16
    u16* rLo = rHi + NBF;
    u16* eHi = (u16*)buf2;                   // 4096*Ii bf16 (codebook chunk)
    u16* eLo = eHi + NBF;

    norms_kernel<<<dim3(24576), dim3(256), 0, stream>>>(cb[0], cb[1], cb[2], cb[3], norms);
    permute_kernel<<<dim3(BFn), dim3(256), 0, stream>>>(x, buf0);
    gemm6_nt<<<dim3(32, 40), dim3(256), 0, stream>>>(buf0, wgate, buf1, Ii, Ii);
    gemm6_nt<<<dim3(32, 40), dim3(256), 0, stream>>>(buf0, wup,   buf2, Ii, Ii);
    silu_mul_kernel<<<dim3((unsigned)(NBF / 1024)), dim3(256), 0, stream>>>(buf1, buf2);
    gemm6_nt<<<dim3(32, 40), dim3(256), 0, stream>>>(buf1, wdown, buf0, Ii, Ii);
    ln_init_kernel<<<dim3(BFn), dim3(256), 0, stream>>>(buf0, x, lns, lnb, best, second);

    const int csz[4] = {8192, 8192, 4096, 4096};
    int noff = 0;
    for (int tcb = 0; tcb < 4; ++tcb) {
        split_kernel<<<dim3(20480), dim3(256), 0, stream>>>(buf0, rHi, rLo);
        for (int c0 = 0; c0 < csz[tcb]; c0 += 4096) {
            split_kernel<<<dim3(20480), dim3(256), 0, stream>>>(
                cb[tcb] + (size_t)c0 * Ii, eHi, eLo);
            score_mfma<<<dim3(32, 32), dim3(256), 0, stream>>>(
                rHi, rLo, eHi, eLo, norms + noff, c0, best, second);
        }
        fixup_kernel<<<dim3(BFn), dim3(256), 0, stream>>>(
            buf0, cb[tcb], norms + noff, best, second);
        update_kernel<<<dim3(BFn), dim3(256), 0, stream>>>(
            buf0, cb[tcb], best, second, outp, lens, tcb, tcb < 3 ? 1 : 0);
        noff += csz[tcb];
    }
    (void)in_sizes; (void)n_in; (void)out_size; (void)ws_size;
}